// Round 1
// baseline (3888.238 us; speedup 1.0000x reference)
//
#include <hip/hip_runtime.h>
#include <math.h>

#define IN_DIM 1024
#define HID 256
#define NE 16
#define ROWS 32
#define BK 32
#define THREADS 256

// smem layout (bytes):
// phase1: xs[32][36] @0      (4608)   transposed x tile (pad 36 keeps 16B align, spreads banks)
//         ws[32][256] @4608  (32768)  W1 tile                      -> end 37376
// phase2: hs[32][256] @0     (32768)  ELU(h) tile
//         w2t[16][260] @32768 (16640) W2 transposed, pad 260 kills 16-way conflict
//         b2s[16]  @49408    (64)
//         ls[32][16] @49472  (2048)   logits tile                  -> end 51520
#define SMEM_BYTES 51520

__global__ __launch_bounds__(THREADS) void router_fp32(
    const float* __restrict__ x, const float* __restrict__ W1,
    const float* __restrict__ b1, const float* __restrict__ W2,
    const float* __restrict__ b2, float* __restrict__ outA,
    float* __restrict__ outL)
{
  __shared__ __align__(16) char smem[SMEM_BYTES];
  float (*xs)[36]   = (float (*)[36])smem;
  float (*ws)[256]  = (float (*)[256])(smem + 4608);
  float (*hs)[256]  = (float (*)[256])smem;
  float (*w2t)[260] = (float (*)[260])(smem + 32768);
  float *b2s        = (float*)(smem + 49408);
  float (*ls)[16]   = (float (*)[16])(smem + 49472);

  const int t  = threadIdx.x;
  const int rg = t >> 5;    // 0..7  -> rows rg*4..rg*4+3
  const int cg = t & 31;    // 0..31 -> cols cg+32m, m=0..7
  const int R0 = blockIdx.x * ROWS;

  float rb1[8];
#pragma unroll
  for (int m = 0; m < 8; m++) rb1[m] = b1[cg + 32*m];

  float acc[4][8];
#pragma unroll
  for (int i = 0; i < 4; i++)
#pragma unroll
    for (int m = 0; m < 8; m++) acc[i][m] = 0.f;

  const int xrow = t >> 3;          // 0..31
  const int xk   = (t & 7) * 4;     // 0..28
  const float* xg = x + (size_t)(R0 + xrow) * IN_DIM + xk;

  for (int k0 = 0; k0 < IN_DIM; k0 += BK) {
    // issue global loads early (reg-staged), write to LDS after barrier
    float4 xv = *(const float4*)(xg + k0);
    float4 wv[8];
#pragma unroll
    for (int i = 0; i < 8; i++) {
      int f4 = t + 256*i;                       // 0..2047 float4s of the tile
      wv[i] = ((const float4*)(W1 + (size_t)(k0 + (f4 >> 6)) * HID))[f4 & 63];
    }
    __syncthreads();   // previous iteration's LDS reads complete
    xs[xk+0][xrow] = xv.x; xs[xk+1][xrow] = xv.y;
    xs[xk+2][xrow] = xv.z; xs[xk+3][xrow] = xv.w;
#pragma unroll
    for (int i = 0; i < 8; i++) {
      int f4 = t + 256*i;
      *(float4*)&ws[f4 >> 6][(f4 & 63) * 4] = wv[i];
    }
    __syncthreads();
#pragma unroll
    for (int k = 0; k < BK; k++) {
      float4 av = *(const float4*)&xs[k][rg * 4];   // broadcast (2 addrs/wave)
      float a0 = av.x, a1v = av.y, a2v = av.z, a3 = av.w;
#pragma unroll
      for (int m = 0; m < 8; m++) {
        float bmv = ws[k][cg + 32*m];               // bank = cg: conflict-free
        acc[0][m] = fmaf(a0,  bmv, acc[0][m]);
        acc[1][m] = fmaf(a1v, bmv, acc[1][m]);
        acc[2][m] = fmaf(a2v, bmv, acc[2][m]);
        acc[3][m] = fmaf(a3,  bmv, acc[3][m]);
      }
    }
  }
  __syncthreads();   // main loop done; LDS is repurposed below

  // bias + ELU -> hs
#pragma unroll
  for (int i = 0; i < 4; i++) {
#pragma unroll
    for (int m = 0; m < 8; m++) {
      float v = acc[i][m] + rb1[m];
      v = v > 0.f ? v : expm1f(v);
      hs[rg*4 + i][cg + 32*m] = v;
    }
  }
  // stage W2 transposed + b2
#pragma unroll
  for (int i = 0; i < 4; i++) {
    int idx4 = t + 256*i;                 // 0..1023 float4s of W2 [256][16]
    float4 wv2 = ((const float4*)W2)[idx4];
    int j  = idx4 >> 2;                   // W2 row (0..255)
    int e0 = (idx4 & 3) * 4;              // starting expert col
    w2t[e0+0][j] = wv2.x; w2t[e0+1][j] = wv2.y;
    w2t[e0+2][j] = wv2.z; w2t[e0+3][j] = wv2.w;
  }
  if (t < 16) b2s[t] = b2[t];
  __syncthreads();

  // logits: 32 rows x 16 experts = 512 outputs, 2 per thread
#pragma unroll
  for (int s = 0; s < 2; s++) {
    int o = t + 256*s;
    int r = o >> 4, e = o & 15;
    float sum = 0.f;
#pragma unroll 8
    for (int j = 0; j < HID; j += 4) {
      float4 hv  = *(const float4*)&hs[r][j];
      float4 wv2 = *(const float4*)&w2t[e][j];
      sum = fmaf(hv.x, wv2.x, sum);
      sum = fmaf(hv.y, wv2.y, sum);
      sum = fmaf(hv.z, wv2.z, sum);
      sum = fmaf(hv.w, wv2.w, sum);
    }
    sum += b2s[e];
    ls[r][e] = sum;
    outL[(size_t)R0 * NE + o] = sum;      // coalesced
  }
  __syncthreads();

  // top-2 + masked softmax (first-occurrence tie-break, matching lax.top_k)
  if (t < ROWS) {
    int r = t;
    float l[16];
#pragma unroll
    for (int e = 0; e < 16; e++) l[e] = ls[r][e];
    int i1 = 0; float m1 = l[0];
#pragma unroll
    for (int e = 1; e < 16; e++) { if (l[e] > m1) { m1 = l[e]; i1 = e; } }
    int i2 = -1; float m2 = -INFINITY;
#pragma unroll
    for (int e = 0; e < 16; e++) { if (e != i1 && l[e] > m2) { m2 = l[e]; i2 = e; } }
    float ex = expf(m2 - m1);       // <= 0 argument: stable
    float s  = 1.f + ex;
    float a1 = 1.f / s;
    float a2 = ex / s;
    float* oa = outA + (size_t)(R0 + r) * NE;
#pragma unroll
    for (int e0 = 0; e0 < 16; e0 += 4) {
      float4 v;
      v.x = (e0+0 == i1) ? a1 : ((e0+0 == i2) ? a2 : 0.f);
      v.y = (e0+1 == i1) ? a1 : ((e0+1 == i2) ? a2 : 0.f);
      v.z = (e0+2 == i1) ? a1 : ((e0+2 == i2) ? a2 : 0.f);
      v.w = (e0+3 == i1) ? a1 : ((e0+3 == i2) ? a2 : 0.f);
      *(float4*)(oa + e0) = v;
    }
  }
}

extern "C" void kernel_launch(void* const* d_in, const int* in_sizes, int n_in,
                              void* d_out, int out_size, void* d_ws, size_t ws_size,
                              hipStream_t stream) {
  const float* x  = (const float*)d_in[0];
  const float* W1 = (const float*)d_in[1];
  const float* b1 = (const float*)d_in[2];
  const float* W2 = (const float*)d_in[3];
  const float* b2 = (const float*)d_in[4];
  float* outA = (float*)d_out;
  const size_t n_tok = (size_t)in_sizes[0] / IN_DIM;
  float* outL = outA + n_tok * NE;

  dim3 grid((unsigned)(n_tok / ROWS));
  dim3 block(THREADS);
  router_fp32<<<grid, block, 0, stream>>>(x, W1, b1, W2, b2, outA, outL);
}

// Round 2
// 2988.814 us; speedup vs baseline: 1.3009x; 1.3009x over previous
//
#include <hip/hip_runtime.h>
#include <math.h>

#define KDIM 1024
#define HID 256
#define NE 16
#define PLANE (HID * KDIM)   // shorts per bf16 plane of W1^T

typedef __attribute__((ext_vector_type(8))) short bf16x8;
typedef __attribute__((ext_vector_type(4))) float f32x4;

__device__ __forceinline__ unsigned short f2bf(float f) {
  union { float f; unsigned u; } v; v.f = f;
  unsigned r = v.u + 0x7fffu + ((v.u >> 16) & 1u);   // RNE
  return (unsigned short)(r >> 16);
}
__device__ __forceinline__ float bf2f(unsigned short h) {
  union { unsigned u; float f; } v; v.u = ((unsigned)h) << 16;
  return v.f;
}

// Split W1[k][c] (fp32) into 3 bf16 planes, stored transposed: W1T_s[c][k].
__global__ void prep_w1(const float* __restrict__ W1, short* __restrict__ wsp) {
  int idx = blockIdx.x * blockDim.x + threadIdx.x;   // 32768 threads
  int k8 = (idx & 127) * 8;
  int c  = idx >> 7;
  bf16x8 o1, o2, o3;
#pragma unroll
  for (int i = 0; i < 8; ++i) {
    float f = W1[(size_t)(k8 + i) * HID + c];
    unsigned short h1 = f2bf(f);  float f1 = bf2f(h1); float r1 = f - f1;
    unsigned short h2 = f2bf(r1); float f2 = bf2f(h2); float r2 = r1 - f2;
    unsigned short h3 = f2bf(r2);
    o1[i] = (short)h1; o2[i] = (short)h2; o3[i] = (short)h3;
  }
  size_t off = (size_t)c * KDIM + k8;
  *(bf16x8*)(wsp + off)             = o1;
  *(bf16x8*)(wsp + PLANE + off)     = o2;
  *(bf16x8*)(wsp + 2 * PLANE + off) = o3;
}

// LDS-free MFMA router. Wave owns 16 rows x 256 cols. 6 split-products.
__global__ __launch_bounds__(256, 3) void gemm_router(
    const float* __restrict__ x, const short* __restrict__ w1t,
    const float* __restrict__ b1, const float* __restrict__ W2,
    const float* __restrict__ b2, float* __restrict__ outA,
    float* __restrict__ outL)
{
  const int t = threadIdx.x;
  const int l = t & 63;
  const int w = t >> 6;           // wave 0..3
  const int q = l & 15;           // frag col / A row
  const int g = l >> 4;           // k-group
  const int rowbase = blockIdx.x * 64 + w * 16;

  const float* xp  = x + (size_t)(rowbase + q) * KDIM + 8 * g;
  const short* bp1 = w1t + (size_t)q * KDIM + 8 * g;
  const short* bp2 = bp1 + PLANE;
  const short* bp3 = bp2 + PLANE;

  f32x4 acc[16];
#pragma unroll
  for (int n = 0; n < 16; ++n) acc[n] = (f32x4){0.f, 0.f, 0.f, 0.f};

  for (int k0 = 0; k0 < KDIM; k0 += 32) {
    float4 av0 = *(const float4*)(xp + k0);
    float4 av1 = *(const float4*)(xp + k0 + 4);
    float af[8] = {av0.x, av0.y, av0.z, av0.w, av1.x, av1.y, av1.z, av1.w};
    bf16x8 a1, a2, a3;
#pragma unroll
    for (int i = 0; i < 8; ++i) {
      float f = af[i];
      unsigned short h1 = f2bf(f);  float f1 = bf2f(h1); float r1 = f - f1;
      unsigned short h2 = f2bf(r1); float f2 = bf2f(h2); float r2 = r1 - f2;
      unsigned short h3 = f2bf(r2);
      a1[i] = (short)h1; a2[i] = (short)h2; a3[i] = (short)h3;
    }
#pragma unroll
    for (int nc = 0; nc < 4; ++nc) {
      bf16x8 bv1[4], bv2[4], bv3[4];
#pragma unroll
      for (int i = 0; i < 4; ++i) {
        size_t boff = (size_t)(nc * 4 + i) * (16 * KDIM) + k0;
        bv1[i] = *(const bf16x8*)(bp1 + boff);
        bv2[i] = *(const bf16x8*)(bp2 + boff);
        bv3[i] = *(const bf16x8*)(bp3 + boff);
      }
#pragma unroll
      for (int i = 0; i < 4; ++i)
        acc[nc*4+i] = __builtin_amdgcn_mfma_f32_16x16x32_bf16(a1, bv1[i], acc[nc*4+i], 0, 0, 0);
#pragma unroll
      for (int i = 0; i < 4; ++i)
        acc[nc*4+i] = __builtin_amdgcn_mfma_f32_16x16x32_bf16(a1, bv2[i], acc[nc*4+i], 0, 0, 0);
#pragma unroll
      for (int i = 0; i < 4; ++i)
        acc[nc*4+i] = __builtin_amdgcn_mfma_f32_16x16x32_bf16(a2, bv1[i], acc[nc*4+i], 0, 0, 0);
#pragma unroll
      for (int i = 0; i < 4; ++i)
        acc[nc*4+i] = __builtin_amdgcn_mfma_f32_16x16x32_bf16(a1, bv3[i], acc[nc*4+i], 0, 0, 0);
#pragma unroll
      for (int i = 0; i < 4; ++i)
        acc[nc*4+i] = __builtin_amdgcn_mfma_f32_16x16x32_bf16(a3, bv1[i], acc[nc*4+i], 0, 0, 0);
#pragma unroll
      for (int i = 0; i < 4; ++i)
        acc[nc*4+i] = __builtin_amdgcn_mfma_f32_16x16x32_bf16(a2, bv2[i], acc[nc*4+i], 0, 0, 0);
    }
  }

  // ---- epilogue: bias + ELU (C layout: col = n*16+q, rows = 4g+j) ----
#pragma unroll
  for (int n = 0; n < 16; ++n) {
    float bv = b1[n * 16 + q];
#pragma unroll
    for (int j = 0; j < 4; ++j) {
      float hv = acc[n][j] + bv;
      acc[n][j] = hv > 0.f ? hv : expm1f(hv);
    }
  }

  // ---- layer 2 partials: p[j][e] over this lane's 16 h-columns ----
  float p[4][16];
#pragma unroll
  for (int j = 0; j < 4; ++j)
#pragma unroll
    for (int e = 0; e < 16; ++e) p[j][e] = 0.f;
#pragma unroll
  for (int n = 0; n < 16; ++n) {
    const float4* w2p = (const float4*)(W2 + (size_t)(n * 16 + q) * NE);
    float4 w20 = w2p[0], w21 = w2p[1], w22 = w2p[2], w23 = w2p[3];
#pragma unroll
    for (int j = 0; j < 4; ++j) {
      float hv = acc[n][j];
      p[j][0]  = fmaf(hv, w20.x, p[j][0]);  p[j][1]  = fmaf(hv, w20.y, p[j][1]);
      p[j][2]  = fmaf(hv, w20.z, p[j][2]);  p[j][3]  = fmaf(hv, w20.w, p[j][3]);
      p[j][4]  = fmaf(hv, w21.x, p[j][4]);  p[j][5]  = fmaf(hv, w21.y, p[j][5]);
      p[j][6]  = fmaf(hv, w21.z, p[j][6]);  p[j][7]  = fmaf(hv, w21.w, p[j][7]);
      p[j][8]  = fmaf(hv, w22.x, p[j][8]);  p[j][9]  = fmaf(hv, w22.y, p[j][9]);
      p[j][10] = fmaf(hv, w22.z, p[j][10]); p[j][11] = fmaf(hv, w22.w, p[j][11]);
      p[j][12] = fmaf(hv, w23.x, p[j][12]); p[j][13] = fmaf(hv, w23.y, p[j][13]);
      p[j][14] = fmaf(hv, w23.z, p[j][14]); p[j][15] = fmaf(hv, w23.w, p[j][15]);
    }
  }

  // ---- reduce-scatter across the 16-lane group ----
  const int hi8 = (q >> 3) & 1;
  const int hi4 = (q >> 2) & 1;
  float r2v[2][16];
#pragma unroll
  for (int e = 0; e < 16; ++e) {
    float send0 = hi8 ? p[0][e] : p[2][e];
    float send1 = hi8 ? p[1][e] : p[3][e];
    float keep0 = hi8 ? p[2][e] : p[0][e];
    float keep1 = hi8 ? p[3][e] : p[1][e];
    r2v[0][e] = keep0 + __shfl_xor(send0, 8);
    r2v[1][e] = keep1 + __shfl_xor(send1, 8);
  }
  float rw[16];
#pragma unroll
  for (int e = 0; e < 16; ++e) {
    float send = hi4 ? r2v[0][e] : r2v[1][e];
    float keep = hi4 ? r2v[1][e] : r2v[0][e];
    rw[e] = keep + __shfl_xor(send, 4);
  }
#pragma unroll
  for (int e = 0; e < 16; ++e) rw[e] += __shfl_xor(rw[e], 2);
#pragma unroll
  for (int e = 0; e < 16; ++e) rw[e] += __shfl_xor(rw[e], 1);

  // + b2
  {
    const float4* b2p = (const float4*)b2;
    float4 B0 = b2p[0], B1 = b2p[1], B2 = b2p[2], B3 = b2p[3];
    rw[0] += B0.x; rw[1] += B0.y; rw[2] += B0.z; rw[3] += B0.w;
    rw[4] += B1.x; rw[5] += B1.y; rw[6] += B1.z; rw[7] += B1.w;
    rw[8] += B2.x; rw[9] += B2.y; rw[10] += B2.z; rw[11] += B2.w;
    rw[12] += B3.x; rw[13] += B3.y; rw[14] += B3.z; rw[15] += B3.w;
  }

  // lane owns row j = 2*hi8 + hi4 of its 4-row band; chunk c4 = q&3
  const int j  = 2 * hi8 + hi4;
  const int c4 = q & 3;

  // top-2 (first-occurrence ties, matches lax.top_k)
  int i1 = 0; float m1 = rw[0];
#pragma unroll
  for (int e = 1; e < 16; ++e) { if (rw[e] > m1) { m1 = rw[e]; i1 = e; } }
  int i2 = -1; float m2 = -INFINITY;
#pragma unroll
  for (int e = 0; e < 16; ++e) { if (e != i1 && rw[e] > m2) { m2 = rw[e]; i2 = e; } }
  float ex = expf(m2 - m1);
  float sden = 1.f + ex;
  float A1 = 1.f / sden;
  float A2 = ex / sden;

  // gather this lane's logit chunk rw[c4*4+k] with static reg indexing
  float lv[4];
#pragma unroll
  for (int k = 0; k < 4; ++k) {
    float v = rw[k];
#pragma unroll
    for (int m = 1; m < 4; ++m) v = (c4 == m) ? rw[m * 4 + k] : v;
    lv[k] = v;
  }
  float4 lgv; lgv.x = lv[0]; lgv.y = lv[1]; lgv.z = lv[2]; lgv.w = lv[3];

  float4 alv;
  {
    int e0 = c4 * 4;
    alv.x = (e0+0 == i1) ? A1 : ((e0+0 == i2) ? A2 : 0.f);
    alv.y = (e0+1 == i1) ? A1 : ((e0+1 == i2) ? A2 : 0.f);
    alv.z = (e0+2 == i1) ? A1 : ((e0+2 == i2) ? A2 : 0.f);
    alv.w = (e0+3 == i1) ? A1 : ((e0+3 == i2) ? A2 : 0.f);
  }

  size_t orow = (size_t)(rowbase + 4 * g + j);
  *(float4*)(outL + orow * NE + c4 * 4) = lgv;
  *(float4*)(outA + orow * NE + c4 * 4) = alv;
}

extern "C" void kernel_launch(void* const* d_in, const int* in_sizes, int n_in,
                              void* d_out, int out_size, void* d_ws, size_t ws_size,
                              hipStream_t stream) {
  const float* x  = (const float*)d_in[0];
  const float* W1 = (const float*)d_in[1];
  const float* b1 = (const float*)d_in[2];
  const float* W2 = (const float*)d_in[3];
  const float* b2 = (const float*)d_in[4];
  short* w1t = (short*)d_ws;
  float* outA = (float*)d_out;
  const size_t n_tok = (size_t)in_sizes[0] / KDIM;
  float* outL = outA + n_tok * NE;

  prep_w1<<<dim3((KDIM * HID / 8) / 256), dim3(256), 0, stream>>>(W1, w1t);
  gemm_router<<<dim3((unsigned)(n_tok / 64)), dim3(256), 0, stream>>>(
      x, w1t, b1, W2, b2, outA, outL);
}

// Round 3
// 675.579 us; speedup vs baseline: 5.7554x; 4.4241x over previous
//
#include <hip/hip_runtime.h>
#include <math.h>

#define KDIM 1024
#define HID 256
#define NE 16
#define NROWS_BLK 128
#define KCH 64
#define NCHUNK (KDIM / KCH)
#define W1T_PLANE (HID * KDIM)
#define W2T_PLANE (NE * HID)
#define SMEM_BYTES 131072

typedef __attribute__((ext_vector_type(8))) _Float16 f16x8;
typedef __attribute__((ext_vector_type(16))) float f32x16;
typedef __attribute__((ext_vector_type(4))) float f32x4;

// ---- prep: scaled 2-plane fp16 split of W1^T and W2^T ----
__global__ void prep_w1(const float* __restrict__ W1, _Float16* __restrict__ w1t) {
  int idx = blockIdx.x * 256 + threadIdx.x;     // 32768
  int col = idx >> 7, k8 = (idx & 127) * 8;
  f16x8 p1, p2;
#pragma unroll
  for (int i = 0; i < 8; ++i) {
    float v = W1[(size_t)(k8 + i) * HID + col];
    _Float16 a = (_Float16)v;
    _Float16 b = (_Float16)((v - (float)a) * 4096.0f);
    p1[i] = a; p2[i] = b;
  }
  size_t off = (size_t)col * KDIM + k8;
  *(f16x8*)(w1t + off) = p1;
  *(f16x8*)(w1t + W1T_PLANE + off) = p2;
}

__global__ void prep_w2(const float* __restrict__ W2, _Float16* __restrict__ w2t) {
  int idx = blockIdx.x * 256 + threadIdx.x;     // 4096
  int e = idx & 15, k = idx >> 4;
  float v = W2[(size_t)k * NE + e];
  _Float16 a = (_Float16)v;
  _Float16 b = (_Float16)((v - (float)a) * 4096.0f);
  w2t[(size_t)e * HID + k] = a;
  w2t[W2T_PLANE + (size_t)e * HID + k] = b;
}

// LDS map (bytes):
//  abuf half0 @0      : [2 planes][128 rows][64 k] fp16, 32768
//  abuf half1 @32768
//  bbuf       @65536  : [2 planes][256 cols][64 k] fp16, 65536
//  epilogue overlay: h1 plane @0 [128][256] fp16; h2' plane @65536
// Swizzle: 16B granule index ^= (row&7)  (rows are 128B in A/B, 512B in h)

__global__ __launch_bounds__(512, 2) void fused_router(
    const float* __restrict__ x, const _Float16* __restrict__ w1t,
    const _Float16* __restrict__ w2t, const float* __restrict__ b1,
    const float* __restrict__ b2, float* __restrict__ outA,
    float* __restrict__ outL)
{
  extern __shared__ char smem[];
  const int t = threadIdx.x;
  const int l = t & 63;
  const int w = t >> 6;              // wave 0..7
  const int rowg = w >> 2, colg = w & 3;
  const int l31 = l & 31, hi = l >> 5;
  const int R0 = blockIdx.x * NROWS_BLK;

  const int arow0 = rowg * 64 + l31;     // + rt*32
  const int bcol0 = colg * 64 + l31;     // + ct*32
  const int s7 = l31 & 7;

  // x loader role: row xr = t>>2, k-segment (t&3)*16 within chunk
  const int xr = t >> 2, xg0 = (t & 3) * 2, xs7 = xr & 7;
  const float* xbase = x + (size_t)(R0 + xr) * KDIM + (t & 3) * 16;

  // B stager role: plane bp = t>>8, col bcol = t&255
  const int bp = t >> 8, bcol = t & 255, bc7 = bcol & 7;
  const _Float16* bsrc0 = w1t + (size_t)bp * W1T_PLANE + (size_t)bcol * KDIM;

  f32x16 acc0[2][2], accA[2][2];
#pragma unroll
  for (int rt = 0; rt < 2; ++rt)
#pragma unroll
    for (int ct = 0; ct < 2; ++ct) {
#pragma unroll
      for (int j = 0; j < 16; ++j) { acc0[rt][ct][j] = 0.f; accA[rt][ct][j] = 0.f; }
    }

  float xvA[16], xvB[16];

#define XLOAD(XV_, TC_) do {                                                  \
    _Pragma("unroll") for (int i_ = 0; i_ < 4; ++i_)                          \
      *(float4*)((XV_) + 4 * i_) =                                            \
        *(const float4*)(xbase + (size_t)(TC_) * KCH + 4 * i_);               \
  } while (0)

#define STAGE(TC_, XV_) do {                                                  \
    const int abw_ = ((TC_) & 1) * 32768;                                     \
    const _Float16* ws_ = bsrc0 + (size_t)(TC_) * KCH;                        \
    f16x8 bst_[8];                                                            \
    _Pragma("unroll") for (int i_ = 0; i_ < 8; ++i_)                          \
      bst_[i_] = *(const f16x8*)(ws_ + 8 * i_);                               \
    f16x8 a1lo_, a1hi_, a2lo_, a2hi_;                                         \
    _Pragma("unroll") for (int j_ = 0; j_ < 16; ++j_) {                       \
      float v_ = (XV_)[j_];                                                   \
      _Float16 h1_ = (_Float16)v_;                                            \
      _Float16 h2_ = (_Float16)((v_ - (float)h1_) * 4096.0f);                 \
      if (j_ < 8) { a1lo_[j_ & 7] = h1_; a2lo_[j_ & 7] = h2_; }               \
      else        { a1hi_[j_ & 7] = h1_; a2hi_[j_ & 7] = h2_; }               \
    }                                                                         \
    *(f16x8*)(smem + abw_ + xr * 128 + ((xg0 ^ xs7) << 4)) = a1lo_;           \
    *(f16x8*)(smem + abw_ + xr * 128 + (((xg0 + 1) ^ xs7) << 4)) = a1hi_;     \
    *(f16x8*)(smem + abw_ + 16384 + xr * 128 + ((xg0 ^ xs7) << 4)) = a2lo_;   \
    *(f16x8*)(smem + abw_ + 16384 + xr * 128 + (((xg0 + 1) ^ xs7) << 4)) = a2hi_; \
    _Pragma("unroll") for (int i_ = 0; i_ < 8; ++i_)                          \
      *(f16x8*)(smem + 65536 + bp * 32768 + bcol * 128 + ((i_ ^ bc7) << 4)) = bst_[i_]; \
  } while (0)

#define COMPUTE(TC_, PREF_, XV_) do {                                         \
    const int abr_ = ((TC_) & 1) * 32768;                                     \
    if (PREF_) { XLOAD(XV_, (TC_) + 2); }                                     \
    _Pragma("unroll") for (int s_ = 0; s_ < 4; ++s_) {                        \
      const int gg_ = (2 * s_ + hi) ^ s7;                                     \
      f16x8 a1f_[2], a2f_[2], b1f_[2], b2f_[2];                               \
      _Pragma("unroll") for (int rt_ = 0; rt_ < 2; ++rt_) {                   \
        int ro_ = (arow0 + rt_ * 32) * 128 + (gg_ << 4);                      \
        a1f_[rt_] = *(const f16x8*)(smem + abr_ + ro_);                       \
        a2f_[rt_] = *(const f16x8*)(smem + abr_ + 16384 + ro_);               \
      }                                                                       \
      _Pragma("unroll") for (int ct_ = 0; ct_ < 2; ++ct_) {                   \
        int co_ = (bcol0 + ct_ * 32) * 128 + (gg_ << 4);                      \
        b1f_[ct_] = *(const f16x8*)(smem + 65536 + co_);                      \
        b2f_[ct_] = *(const f16x8*)(smem + 98304 + co_);                      \
      }                                                                       \
      _Pragma("unroll") for (int rt_ = 0; rt_ < 2; ++rt_)                     \
      _Pragma("unroll") for (int ct_ = 0; ct_ < 2; ++ct_) {                   \
        acc0[rt_][ct_] = __builtin_amdgcn_mfma_f32_32x32x16_f16(              \
            a1f_[rt_], b1f_[ct_], acc0[rt_][ct_], 0, 0, 0);                   \
        accA[rt_][ct_] = __builtin_amdgcn_mfma_f32_32x32x16_f16(              \
            a1f_[rt_], b2f_[ct_], accA[rt_][ct_], 0, 0, 0);                   \
        accA[rt_][ct_] = __builtin_amdgcn_mfma_f32_32x32x16_f16(              \
            a2f_[rt_], b1f_[ct_], accA[rt_][ct_], 0, 0, 0);                   \
      }                                                                       \
    }                                                                         \
  } while (0)

  // prologue
  XLOAD(xvA, 0);
  XLOAD(xvB, 1);
  STAGE(0, xvA);
  __syncthreads();

#pragma unroll 1
  for (int tcb = 0; tcb < NCHUNK; tcb += 2) {
    COMPUTE(tcb, tcb + 2 < NCHUNK, xvA);
    __syncthreads();
    STAGE(tcb + 1, xvB);
    __syncthreads();
    COMPUTE(tcb + 1, tcb + 3 < NCHUNK, xvB);
    __syncthreads();
    if (tcb + 2 < NCHUNK) STAGE(tcb + 2, xvA);
    __syncthreads();
  }

  // ---- epilogue: h = acc0 + 2^-12 accA + b1 -> ELU -> split -> LDS planes ----
  const float c12 = 1.0f / 4096.0f;
#pragma unroll
  for (int ct = 0; ct < 2; ++ct) {
    int col = bcol0 + ct * 32;
    float bc = b1[col];
    int cg = col >> 3, cb = (col & 7) * 2;
#pragma unroll
    for (int rt = 0; rt < 2; ++rt) {
#pragma unroll
      for (int r = 0; r < 16; ++r) {
        int row = rowg * 64 + rt * 32 + (r & 3) + 8 * (r >> 2) + 4 * hi;
        float v = acc0[rt][ct][r] + c12 * accA[rt][ct][r] + bc;
        v = v > 0.f ? v : expm1f(v);
        _Float16 h1 = (_Float16)v;
        _Float16 h2 = (_Float16)((v - (float)h1) * 4096.0f);
        int off = row * 512 + ((cg ^ (row & 7)) << 4) + cb;
        *(_Float16*)(smem + off) = h1;
        *(_Float16*)(smem + 65536 + off) = h2;
      }
    }
  }
  __syncthreads();

  // ---- layer 2: logits^T = W2T . h^T (16x16x32 f16, scaled split) ----
  const int tok = l & 15, g2 = l >> 4;
  const int hrow = w * 16 + tok;
  f32x4 L0, LA;
#pragma unroll
  for (int j = 0; j < 4; ++j) { L0[j] = 0.f; LA[j] = 0.f; }
  const _Float16* w2a = w2t + (size_t)(l & 15) * HID;
  const _Float16* w2b = w2a + W2T_PLANE;
#pragma unroll
  for (int kt = 0; kt < 8; ++kt) {
    int gg = (kt * 4 + g2) ^ (hrow & 7);
    f16x8 hb1 = *(const f16x8*)(smem + hrow * 512 + (gg << 4));
    f16x8 hb2 = *(const f16x8*)(smem + 65536 + hrow * 512 + (gg << 4));
    f16x8 wa = *(const f16x8*)(w2a + kt * 32 + 8 * g2);
    f16x8 wb = *(const f16x8*)(w2b + kt * 32 + 8 * g2);
    L0 = __builtin_amdgcn_mfma_f32_16x16x32_f16(wa, hb1, L0, 0, 0, 0);
    LA = __builtin_amdgcn_mfma_f32_16x16x32_f16(wa, hb2, LA, 0, 0, 0);
    LA = __builtin_amdgcn_mfma_f32_16x16x32_f16(wb, hb1, LA, 0, 0, 0);
  }

  float4 b2v = *(const float4*)(b2 + 4 * g2);
  float L[4];
  L[0] = L0[0] + c12 * LA[0] + b2v.x;
  L[1] = L0[1] + c12 * LA[1] + b2v.y;
  L[2] = L0[2] + c12 * LA[2] + b2v.z;
  L[3] = L0[3] + c12 * LA[3] + b2v.w;

  float o1[4], o2[4], o3[4];
#pragma unroll
  for (int j = 0; j < 4; ++j) o1[j] = __shfl_xor(L[j], 16);
#pragma unroll
  for (int j = 0; j < 4; ++j) o2[j] = __shfl_xor(L[j], 32);
#pragma unroll
  for (int j = 0; j < 4; ++j) o3[j] = __shfl_xor(o1[j], 32);

  float all16[16];
#pragma unroll
  for (int c = 0; c < 4; ++c) {
    int xg = c ^ g2;
#pragma unroll
    for (int j = 0; j < 4; ++j) {
      float v = L[j];
      v = (xg == 1) ? o1[j] : v;
      v = (xg == 2) ? o2[j] : v;
      v = (xg == 3) ? o3[j] : v;
      all16[c * 4 + j] = v;
    }
  }

  int i1 = 0; float m1 = all16[0];
#pragma unroll
  for (int e = 1; e < 16; ++e) { if (all16[e] > m1) { m1 = all16[e]; i1 = e; } }
  int i2 = -1; float m2 = -INFINITY;
#pragma unroll
  for (int e = 0; e < 16; ++e) { if (e != i1 && all16[e] > m2) { m2 = all16[e]; i2 = e; } }
  float ex = expf(m2 - m1);
  float sden = 1.f + ex;
  float A1 = 1.f / sden;
  float A2 = ex / sden;

  int e0 = 4 * g2;
  float4 alv;
  alv.x = (e0 + 0 == i1) ? A1 : ((e0 + 0 == i2) ? A2 : 0.f);
  alv.y = (e0 + 1 == i1) ? A1 : ((e0 + 1 == i2) ? A2 : 0.f);
  alv.z = (e0 + 2 == i1) ? A1 : ((e0 + 2 == i2) ? A2 : 0.f);
  alv.w = (e0 + 3 == i1) ? A1 : ((e0 + 3 == i2) ? A2 : 0.f);

  size_t orow = (size_t)(R0 + w * 16 + tok);
  float4 lgv; lgv.x = L[0]; lgv.y = L[1]; lgv.z = L[2]; lgv.w = L[3];
  *(float4*)(outL + orow * NE + e0) = lgv;
  *(float4*)(outA + orow * NE + e0) = alv;
}

extern "C" void kernel_launch(void* const* d_in, const int* in_sizes, int n_in,
                              void* d_out, int out_size, void* d_ws, size_t ws_size,
                              hipStream_t stream) {
  const float* x  = (const float*)d_in[0];
  const float* W1 = (const float*)d_in[1];
  const float* b1 = (const float*)d_in[2];
  const float* W2 = (const float*)d_in[3];
  const float* b2 = (const float*)d_in[4];
  _Float16* w1t = (_Float16*)d_ws;
  _Float16* w2t = w1t + 2 * W1T_PLANE;
  float* outA = (float*)d_out;
  const size_t n_tok = (size_t)in_sizes[0] / KDIM;
  float* outL = outA + n_tok * NE;

  prep_w1<<<dim3(128), dim3(256), 0, stream>>>(W1, w1t);
  prep_w2<<<dim3(16), dim3(256), 0, stream>>>(W2, w2t);

  hipFuncSetAttribute((const void*)fused_router,
                      hipFuncAttributeMaxDynamicSharedMemorySize, SMEM_BYTES);
  fused_router<<<dim3((unsigned)(n_tok / NROWS_BLK)), dim3(512), SMEM_BYTES, stream>>>(
      x, w1t, w2t, b1, b2, outA, outL);
}

// Round 6
// 575.556 us; speedup vs baseline: 6.7556x; 1.1738x over previous
//
#include <hip/hip_runtime.h>
#include <math.h>

#define KDIM 1024
#define HID 256
#define NE 16
#define ROWS_BLK 64
#define KCH 32
#define NCHUNK 32
#define CH_BYTES 32768            // B chunk image: 2p*4kg*256col*16B
#define W2T_PLANE (NE * HID)
#define BBASE 16384               // A dbuf: 2*8KB @0 ; B dbuf: 2*32KB @16384
#define BB_STRIDE 32768
#define SMEM_BYTES 81920

typedef __attribute__((ext_vector_type(4))) _Float16 f16x4;
typedef __attribute__((ext_vector_type(8))) _Float16 f16x8;
typedef __attribute__((ext_vector_type(16))) float f32x16;
typedef __attribute__((ext_vector_type(4))) float f32x4;

__device__ __forceinline__ void gld16(const void* g, void* s) {
  __builtin_amdgcn_global_load_lds(
      (const __attribute__((address_space(1))) void*)g,
      (__attribute__((address_space(3))) void*)s, 16, 0, 0);
}

// R3-proven plane defs: p1 = fl16(v), p2 = fl16((v - p1)*4096).
// Image layout: [c][p][kg][col] 16B granules (bytes: c*32768 + p*16384 + kg*4096 + col*16)
__global__ void prep_w1(const float* __restrict__ W1, _Float16* __restrict__ img) {
  int idx = blockIdx.x * 256 + threadIdx.x;   // 0..32767
  int col = idx & 255, kgl = idx >> 8;        // kgl 0..127
  int c = kgl >> 2, kg = kgl & 3, k8 = kgl * 8;
  f16x8 p1, p2;
#pragma unroll
  for (int i = 0; i < 8; ++i) {
    float v = W1[(size_t)(k8 + i) * HID + col];
    _Float16 a = (_Float16)v;
    _Float16 b = (_Float16)((v - (float)a) * 4096.0f);
    p1[i] = a; p2[i] = b;
  }
  size_t off = (size_t)c * 16384 + (size_t)kg * 2048 + (size_t)col * 8;  // shorts
  *(f16x8*)(img + off) = p1;
  *(f16x8*)(img + off + 8192) = p2;
}

__global__ void prep_w2(const float* __restrict__ W2, _Float16* __restrict__ w2t) {
  int idx = blockIdx.x * 256 + threadIdx.x;   // 0..4095
  int e = idx & 15, k = idx >> 4;
  float v = W2[(size_t)k * NE + e];
  _Float16 a = (_Float16)v;
  _Float16 b = (_Float16)((v - (float)a) * 4096.0f);
  w2t[(size_t)e * HID + k] = a;
  w2t[W2T_PLANE + (size_t)e * HID + k] = b;
}

__global__ __launch_bounds__(512, 4) void fused_router(
    const float* __restrict__ x, const _Float16* __restrict__ w1img,
    const _Float16* __restrict__ w2t, const float* __restrict__ bias1,
    const float* __restrict__ bias2, float* __restrict__ outA,
    float* __restrict__ outL)
{
  extern __shared__ char smem[];
  const int t = threadIdx.x, l = t & 63, w = t >> 6;
  const int rowg = w >> 2, colg = w & 3;     // 2 x 4 waves: 64 rows x 256 cols
  const int l31 = l & 31, hi = l >> 5;
  const int R0 = blockIdx.x * ROWS_BLK;
  const int arow = rowg * 32 + l31;
  const int bcol0 = colg * 64 + l31;         // + 32*ct

  // x loader: row xr = t>>3 (0..63), float-quad xq = t&7 (k = xq*4..+3)
  const int xr = t >> 3, xq = t & 7;
  const float* xbase = x + (size_t)(R0 + xr) * KDIM + xq * 4;
  const int akg = xq >> 1, asub = (xq & 1) * 8;   // A write: granule, byte sub-offset

  // B stager: thread t copies image bytes t*16 + i*8192 (linear)
  const char* ibase = (const char*)w1img + t * 16;

  f32x16 acc0[2], accA[2];
#pragma unroll
  for (int ct = 0; ct < 2; ++ct)
#pragma unroll
    for (int j = 0; j < 16; ++j) { acc0[ct][j] = 0.f; accA[ct][j] = 0.f; }

  float4 xv;

#define XLOAD(C_) do { xv = *(const float4*)(xbase + (size_t)(C_) * KCH); } while (0)

#define BSTAGE(C_, BS_) do {                                                  \
    const char* is_ = ibase + (size_t)(C_) * CH_BYTES;                        \
    char* bd_ = smem + BBASE + (BS_) * BB_STRIDE + t * 16;                    \
    gld16(is_,         bd_);                                                  \
    gld16(is_ + 8192,  bd_ + 8192);                                           \
    gld16(is_ + 16384, bd_ + 16384);                                          \
    gld16(is_ + 24576, bd_ + 24576);                                          \
  } while (0)

#define ASPLIT(BS_) do {                                                      \
    float vals_[4] = {xv.x, xv.y, xv.z, xv.w};                                \
    f16x4 pa_, pb_;                                                           \
    _Pragma("unroll") for (int j_ = 0; j_ < 4; ++j_) {                        \
      float v_ = vals_[j_];                                                   \
      _Float16 a_ = (_Float16)v_;                                             \
      _Float16 b_ = (_Float16)((v_ - (float)a_) * 4096.0f);                   \
      pa_[j_] = a_; pb_[j_] = b_;                                             \
    }                                                                         \
    int ao_ = (BS_) * 8192 + akg * 1024 + xr * 16 + asub;                     \
    *(f16x4*)(smem + ao_) = pa_;                                              \
    *(f16x4*)(smem + ao_ + 4096) = pb_;                                       \
  } while (0)

#define COMPUTE(BS_) do {                                                     \
    _Pragma("unroll") for (int s_ = 0; s_ < 2; ++s_) {                        \
      const int gg_ = 2 * s_ + hi;                                            \
      int ao_ = (BS_) * 8192 + gg_ * 1024 + arow * 16;                        \
      f16x8 a1_ = *(const f16x8*)(smem + ao_);                                \
      f16x8 a2_ = *(const f16x8*)(smem + ao_ + 4096);                         \
      _Pragma("unroll") for (int ct_ = 0; ct_ < 2; ++ct_) {                   \
        int bo_ = BBASE + (BS_) * BB_STRIDE + gg_ * 4096                      \
                  + (bcol0 + 32 * ct_) * 16;                                  \
        f16x8 b1_ = *(const f16x8*)(smem + bo_);                              \
        f16x8 b2_ = *(const f16x8*)(smem + bo_ + 16384);                      \
        acc0[ct_] = __builtin_amdgcn_mfma_f32_32x32x16_f16(                   \
            a1_, b1_, acc0[ct_], 0, 0, 0);                                    \
        accA[ct_] = __builtin_amdgcn_mfma_f32_32x32x16_f16(                   \
            a1_, b2_, accA[ct_], 0, 0, 0);                                    \
        accA[ct_] = __builtin_amdgcn_mfma_f32_32x32x16_f16(                   \
            a2_, b1_, accA[ct_], 0, 0, 0);                                    \
      }                                                                       \
    }                                                                         \
  } while (0)

  // prologue
  XLOAD(0);
  BSTAGE(0, 0);
  ASPLIT(0);
  XLOAD(1);
  __syncthreads();

  int bsel = 0;
#pragma unroll 1
  for (int c = 0; c < NCHUNK; ++c) {
    if (c + 1 < NCHUNK) {
      BSTAGE(c + 1, bsel ^ 1);
      ASPLIT(bsel ^ 1);
      if (c + 2 < NCHUNK) XLOAD(c + 2);
    }
    COMPUTE(bsel);
    __syncthreads();
    bsel ^= 1;
  }

  // ---- epilogue (R3-proven mappings, 64-row block) ----
  const float c12 = 1.0f / 4096.0f;
  const int tok = l & 15, g2 = l >> 4;

  // h = acc0 + accA/4096 + b1 -> ELU -> split -> LDS planes (h1 @0, h2 @32768)
#pragma unroll
  for (int ct = 0; ct < 2; ++ct) {
    int col = bcol0 + 32 * ct;
    float bc = bias1[col];
    int cg = col >> 3, cb = (col & 7) * 2;
#pragma unroll
    for (int r = 0; r < 16; ++r) {
      int row = rowg * 32 + (r & 3) + 8 * (r >> 2) + 4 * hi;   // 0..63
      float v = acc0[ct][r] + c12 * accA[ct][r] + bc;
      v = v > 0.f ? v : expm1f(v);
      _Float16 h1 = (_Float16)v;
      _Float16 h2 = (_Float16)((v - (float)h1) * 4096.0f);
      int off = row * 512 + ((cg ^ (row & 7)) << 4) + cb;
      *(_Float16*)(smem + off) = h1;
      *(_Float16*)(smem + 32768 + off) = h2;
    }
  }
  __syncthreads();

  if (w < 4) {
    int tloc = w * 16 + tok;                 // 0..63
    f32x4 L0, LA;
#pragma unroll
    for (int j = 0; j < 4; ++j) { L0[j] = 0.f; LA[j] = 0.f; }
    const _Float16* w2a = w2t + (size_t)tok * HID;
    const _Float16* w2b = w2a + W2T_PLANE;
#pragma unroll
    for (int kt = 0; kt < 8; ++kt) {
      int gg = (kt * 4 + g2) ^ (tloc & 7);
      f16x8 hb1 = *(const f16x8*)(smem + tloc * 512 + (gg << 4));
      f16x8 hb2 = *(const f16x8*)(smem + 32768 + tloc * 512 + (gg << 4));
      f16x8 wa = *(const f16x8*)(w2a + kt * 32 + 8 * g2);
      f16x8 wb = *(const f16x8*)(w2b + kt * 32 + 8 * g2);
      L0 = __builtin_amdgcn_mfma_f32_16x16x32_f16(wa, hb1, L0, 0, 0, 0);
      LA = __builtin_amdgcn_mfma_f32_16x16x32_f16(wa, hb2, LA, 0, 0, 0);
      LA = __builtin_amdgcn_mfma_f32_16x16x32_f16(wb, hb1, LA, 0, 0, 0);
    }
    float4 b2v = *(const float4*)(bias2 + 4 * g2);
    float L[4];
    L[0] = L0[0] + c12 * LA[0] + b2v.x;
    L[1] = L0[1] + c12 * LA[1] + b2v.y;
    L[2] = L0[2] + c12 * LA[2] + b2v.z;
    L[3] = L0[3] + c12 * LA[3] + b2v.w;

    float o1[4], o2[4], o3[4];
#pragma unroll
    for (int j = 0; j < 4; ++j) o1[j] = __shfl_xor(L[j], 16);
#pragma unroll
    for (int j = 0; j < 4; ++j) o2[j] = __shfl_xor(L[j], 32);
#pragma unroll
    for (int j = 0; j < 4; ++j) o3[j] = __shfl_xor(o1[j], 32);

    float all16[16];
#pragma unroll
    for (int cq = 0; cq < 4; ++cq) {
      int xg = cq ^ g2;
#pragma unroll
      for (int j = 0; j < 4; ++j) {
        float v = L[j];
        v = (xg == 1) ? o1[j] : v;
        v = (xg == 2) ? o2[j] : v;
        v = (xg == 3) ? o3[j] : v;
        all16[cq * 4 + j] = v;
      }
    }

    int i1 = 0; float m1 = all16[0];
#pragma unroll
    for (int e = 1; e < 16; ++e) { if (all16[e] > m1) { m1 = all16[e]; i1 = e; } }
    int i2 = -1; float m2 = -INFINITY;
#pragma unroll
    for (int e = 0; e < 16; ++e) { if (e != i1 && all16[e] > m2) { m2 = all16[e]; i2 = e; } }
    float ex = expf(m2 - m1);
    float sden = 1.f + ex;
    float A1 = 1.f / sden;
    float A2 = ex / sden;

    int e0 = 4 * g2;
    float4 alv;
    alv.x = (e0 + 0 == i1) ? A1 : ((e0 + 0 == i2) ? A2 : 0.f);
    alv.y = (e0 + 1 == i1) ? A1 : ((e0 + 1 == i2) ? A2 : 0.f);
    alv.z = (e0 + 2 == i1) ? A1 : ((e0 + 2 == i2) ? A2 : 0.f);
    alv.w = (e0 + 3 == i1) ? A1 : ((e0 + 3 == i2) ? A2 : 0.f);

    size_t orow = (size_t)(R0 + tloc);
    float4 lgv; lgv.x = L[0]; lgv.y = L[1]; lgv.z = L[2]; lgv.w = L[3];
    *(float4*)(outL + orow * NE + e0) = lgv;
    *(float4*)(outA + orow * NE + e0) = alv;
  }
#undef XLOAD
#undef BSTAGE
#undef ASPLIT
#undef COMPUTE
}

extern "C" void kernel_launch(void* const* d_in, const int* in_sizes, int n_in,
                              void* d_out, int out_size, void* d_ws, size_t ws_size,
                              hipStream_t stream) {
  const float* x  = (const float*)d_in[0];
  const float* W1 = (const float*)d_in[1];
  const float* b1 = (const float*)d_in[2];
  const float* W2 = (const float*)d_in[3];
  const float* b2 = (const float*)d_in[4];
  _Float16* w1img = (_Float16*)d_ws;
  _Float16* w2t = w1img + (size_t)NCHUNK * (CH_BYTES / 2);
  float* outA = (float*)d_out;
  const size_t n_tok = (size_t)in_sizes[0] / KDIM;
  float* outL = outA + n_tok * NE;

  prep_w1<<<dim3(128), dim3(256), 0, stream>>>(W1, w1img);
  prep_w2<<<dim3(16), dim3(256), 0, stream>>>(W2, w2t);

  hipFuncSetAttribute((const void*)fused_router,
                      hipFuncAttributeMaxDynamicSharedMemorySize, SMEM_BYTES);
  fused_router<<<dim3((unsigned)(n_tok / ROWS_BLK)), dim3(512), SMEM_BYTES, stream>>>(
      x, w1img, w2t, b1, b2, outA, outL);
}